// Round 9
// baseline (222.271 us; speedup 1.0000x reference)
//
#include <hip/hip_runtime.h>

// ---------------------------------------------------------------------------
// SelfAttention fused pipeline for MI355X (gfx950)
// B=4 S=1024 DIM=2048 H=16 KV=4 HD=128 ROPE_DIM=64
//
// Stages (all on `stream`):
//  1) casts fp32 -> bf16 (x | Wq,Wk,Wv fused | Wproj)
//  2) gemm256<256>: qkv = xb @ Wcat^T  (256^2 tile, BK=64 dbuf, 2-phase split,
//     full-width LDS swizzle, counted-cover vmcnt, setprio, XCD-chunked)
//  3) normrope: RMSNorm + partial RoPE in-place (q pre-scaled to log2 domain)
//  3b) vtrans: V -> Vt_global[b,kvh][d][kv] (pre-swizzled for LDS staging)
//  4) attn_fwd: causal flash attention + v-proj correction -> y bf16
//  5) gemm256<128>: out = y @ Wproj^T  (256x128 tile -> 256 blocks, fp32 out)
// ---------------------------------------------------------------------------

typedef __attribute__((ext_vector_type(8))) __bf16 bf16x8;
typedef __attribute__((ext_vector_type(4))) __bf16 bf16x4;
typedef __attribute__((ext_vector_type(4))) float f32x4;

static_assert(sizeof(__bf16) == 2, "bf16 size");

#define MFMA16x16x32(a, b, c) __builtin_amdgcn_mfma_f32_16x16x32_bf16((a), (b), (c), 0, 0, 0)

#if __has_builtin(__builtin_amdgcn_exp2f)
#define EXP2(x) __builtin_amdgcn_exp2f(x)
#else
#define EXP2(x) exp2f(x)
#endif

__device__ __forceinline__ void gload_lds16(const void* g, void* l) {
  __builtin_amdgcn_global_load_lds((const __attribute__((address_space(1))) void*)g,
                                   (__attribute__((address_space(3))) void*)l, 16, 0, 0);
}

// ---------------- 1) cast fp32 -> bf16 (vectorized) ----------------
__global__ __launch_bounds__(256) void cast_f2b(const float* __restrict__ in,
                                                __bf16* __restrict__ out, int n4) {
  int i = blockIdx.x * blockDim.x + threadIdx.x;
  const int stride = gridDim.x * blockDim.x;
  for (; i < n4; i += stride) {
    f32x4 v = ((const f32x4*)in)[i];
    bf16x4 o;
    o[0] = (__bf16)v[0];
    o[1] = (__bf16)v[1];
    o[2] = (__bf16)v[2];
    o[3] = (__bf16)v[3];
    ((bf16x4*)out)[i] = o;
  }
}

// fused cast of Wq(2048x2048) | Wk(512x2048) | Wv(512x2048) into Wb concat
__global__ __launch_bounds__(256) void cast3_f2b(const float* __restrict__ wq,
                                                 const float* __restrict__ wk,
                                                 const float* __restrict__ wv,
                                                 __bf16* __restrict__ out) {
  const int n1 = 2048 * 2048 / 4, n2 = 512 * 2048 / 4;
  const int ntot = n1 + 2 * n2;
  int i = blockIdx.x * blockDim.x + threadIdx.x;
  const int stride = gridDim.x * blockDim.x;
  for (; i < ntot; i += stride) {
    const float* src;
    int j = i;
    if (j < n1) {
      src = wq;
    } else if (j < n1 + n2) {
      src = wk;
      j -= n1;
    } else {
      src = wv;
      j -= n1 + n2;
    }
    f32x4 v = ((const f32x4*)src)[j];
    bf16x4 o;
    o[0] = (__bf16)v[0];
    o[1] = (__bf16)v[1];
    o[2] = (__bf16)v[2];
    o[3] = (__bf16)v[3];
    ((bf16x4*)out)[i] = o;
  }
}

// ---------------- 2/5) 256-wide BK=64 two-phase B^T GEMM ----------------
// C[M,N] = A[M,K]*B[N,K]^T. Tile 256xBN, BK=64, 8 waves (2Mx4N), per-wave
// 128 x BN/4. Double-buffered LDS; stage(kt+1) fully issued before the 64-MFMA
// body; ONE vmcnt(0) drain per K-tile (covered by ~64 MFMA/wave); mid-tile raw
// s_barrier splits kk-halves (caps live frags -> no spill; waves phase-locked);
// setprio around MFMA clusters. LDS [.][64] col-group swizzled by row&7
// (quarter-wave: 8 slots x 2 lanes = conflict-free), staged via
// inverse-swizzled GLOBAL source + linear global_load_lds dest.
// 1-D grid, XCD-chunked (nwg % 8 == 0), bm-major within chunk.
template <int BN, typename CT>
__global__ __launch_bounds__(512) void gemm256(const __bf16* __restrict__ A,
                                               const __bf16* __restrict__ B,
                                               CT* __restrict__ C, int N, int K,
                                               int nbn) {
  constexpr int NR = BN / 64;  // n-frags per wave: 4 (BN=256) or 2 (BN=128)
  __shared__ __bf16 As[2][256 * 64];
  __shared__ __bf16 Bs[2][BN * 64];

  const int nwg = gridDim.x;
  const int id = blockIdx.x;
  const int xid = (id & 7) * (nwg >> 3) + (id >> 3);
  const int bm = xid / nbn;
  const int bn = xid - bm * nbn;

  const int t = threadIdx.x;
  const int l = t & 63, w = t >> 6;  // 8 waves
  const int wr = w >> 2, wc = w & 3;
  const int lr = l & 15, lk = l >> 4;
  const __bf16* Ab = A + (size_t)bm * 256 * K;
  const __bf16* Bb = B + (size_t)bn * BN * K;

  // staging: round r covers local rows r*64 + (t>>3), dest col-group t&7;
  // source col-group = (t&7) ^ (row&7)  (row&7 == (t>>3)&7 since 64%8==0)
  const int srow = t >> 3;
  const int scol = ((t & 7) ^ (srow & 7)) << 3;

  auto stage = [&](int kt, int buf) {
    const int k0 = kt << 6;
#pragma unroll
    for (int r = 0; r < 4; ++r)
      gload_lds16(Ab + (size_t)(r * 64 + srow) * K + k0 + scol,
                  &As[buf][r * 4096 + t * 8]);
#pragma unroll
    for (int r = 0; r < BN / 64; ++r)
      gload_lds16(Bb + (size_t)(r * 64 + srow) * K + k0 + scol,
                  &Bs[buf][r * 4096 + t * 8]);
  };

  f32x4 acc[8][NR] = {};

  stage(0, 0);
  __syncthreads();  // drains vmcnt -> buf0 ready

  const int NT = K >> 6;
  for (int kt = 0; kt < NT; ++kt) {
    const int cur = kt & 1;
    if (kt + 1 < NT) stage(kt + 1, cur ^ 1);  // all stage loads issued up front

#pragma unroll
    for (int kk = 0; kk < 2; ++kk) {
      bf16x8 af[8], bfr[NR];
#pragma unroll
      for (int m = 0; m < 8; ++m) {
        const int row = wr * 128 + m * 16 + lr;
        const int cg = (kk * 4 + lk) ^ (row & 7);
        af[m] = *(const bf16x8*)&As[cur][row * 64 + cg * 8];
      }
#pragma unroll
      for (int n = 0; n < NR; ++n) {
        const int row = wc * (16 * NR) + n * 16 + lr;
        const int cg = (kk * 4 + lk) ^ (row & 7);
        bfr[n] = *(const bf16x8*)&Bs[cur][row * 64 + cg * 8];
      }
      __builtin_amdgcn_s_setprio(1);
#pragma unroll
      for (int m = 0; m < 8; ++m)
#pragma unroll
        for (int n = 0; n < NR; ++n) acc[m][n] = MFMA16x16x32(af[m], bfr[n], acc[m][n]);
      __builtin_amdgcn_s_setprio(0);
      if (kk == 0) {
        __builtin_amdgcn_s_barrier();  // light mid barrier: no vmcnt drain
      } else {
        asm volatile("s_waitcnt vmcnt(0)" ::: "memory");  // next buf staged
        __builtin_amdgcn_s_barrier();
      }
    }
  }

  // epilogue
#pragma unroll
  for (int m = 0; m < 8; ++m) {
    const int row0 = bm * 256 + wr * 128 + m * 16 + lk * 4;
#pragma unroll
    for (int n = 0; n < NR; ++n) {
      const int col = bn * BN + wc * (16 * NR) + n * 16 + lr;
#pragma unroll
      for (int i = 0; i < 4; ++i) C[(size_t)(row0 + i) * N + col] = (CT)acc[m][n][i];
    }
  }
}

// ---------------- 3) RMSNorm + partial RoPE (in place on qkv) ----------------
// q rows additionally scaled by (1/sqrt(128))*log2(e) -> attention scores
// come out of QK^T already in log2 domain (softmax uses exp2 directly).
__global__ __launch_bounds__(256) void normrope(__bf16* __restrict__ qkv) {
  const int w = threadIdx.x >> 6, l = threadIdx.x & 63;
  const int idx = blockIdx.x * 4 + w;
  int m, col0;
  bool isq;
  if (idx < 65536) {
    m = idx >> 4;
    col0 = (idx & 15) << 7;
    isq = true;
  } else {
    const int j = idx - 65536;
    m = j >> 2;
    col0 = 2048 + ((j & 3) << 7);
    isq = false;
  }
  const int s = m & 1023;
  __bf16* p = qkv + (size_t)m * 3072 + col0;
  float v0 = (float)p[l];
  float v1 = (float)p[l + 64];
  float ss = v0 * v0 + v1 * v1;
#pragma unroll
  for (int off = 1; off < 64; off <<= 1) ss += __shfl_xor(ss, off);
  float sc = rsqrtf(ss * (1.0f / 128.0f) + 1.1920928955078125e-07f);
  v0 *= sc;
  v1 *= sc;
  const float other = __shfl_xor(v0, 32);
  const int j = l & 31;
  const float ang = (float)s * powf(10000.0f, -(float)j * 0.03125f);
  const float cs = cosf(ang), sn = sinf(ang);
  float r0;
  if (l < 32)
    r0 = v0 * cs + other * sn;
  else
    r0 = -other * sn + v0 * cs;
  if (isq) {
    const float qs = 0.1275174457f;  // (1/sqrt(128)) * log2(e)
    r0 *= qs;
    v1 *= qs;
  }
  p[l] = (__bf16)r0;
  p[l + 64] = (__bf16)v1;
}

// ---------------- 3b) V transpose: Vt[b,kvh][d][kv ^ ((d&7)<<3)] -------------
__global__ __launch_bounds__(256) void vtrans(const __bf16* __restrict__ qkv,
                                              __bf16* __restrict__ vt) {
  __shared__ __bf16 L[64 * 128];
  const int tile = blockIdx.x;  // (b*4+kvh)*16 + st
  const int st = tile & 15, bk = tile >> 4;
  const int b = bk >> 2, kvh = bk & 3;
  const int t = threadIdx.x;
  const int s0 = st * 64;
  const __bf16* src = qkv + ((size_t)(b * 1024 + s0)) * 3072 + 2560 + kvh * 128;
#pragma unroll
  for (int r = 0; r < 4; ++r) {
    const int off = r * 2048 + t * 8;
    const int s = off >> 7, d = off & 127;
    bf16x8 v = *(const bf16x8*)(src + (size_t)s * 3072 + d);
    *(bf16x8*)&L[s * 128 + (d ^ ((s & 7) << 3) ^ (((s >> 3) & 7) << 3))] = v;
  }
  __syncthreads();
  __bf16* dst = vt + (size_t)bk * 128 * 1024;
#pragma unroll
  for (int r = 0; r < 4; ++r) {
    const int off = r * 2048 + t * 8;
    const int d = off >> 6, sc = off & 63;
    bf16x8 v;
#pragma unroll
    for (int j = 0; j < 8; ++j) {
      const int s = sc + j;
      v[j] = L[s * 128 + (d ^ ((s & 7) << 3) ^ (((s >> 3) & 7) << 3))];
    }
    *(bf16x8*)&dst[(size_t)d * 1024 + ((s0 + sc) ^ ((d & 7) << 3))] = v;
  }
}

// ---------------- 4) causal flash attention + v-projection correction ------
// 256 blocks (=1/CU), each handles ONE (b,h) and TWO q-tiles (pr, 7-pr)
// sequentially -> exactly 18 kv-iterations/block. XCD grouping: blocks of one
// (b,kvh) group share an XCD (id&7) so K/V stays L2-resident.
__global__ __launch_bounds__(512) void attn_fwd(const __bf16* __restrict__ qkv,
                                                const __bf16* __restrict__ vt,
                                                __bf16* __restrict__ y) {
  const int id = blockIdx.x;
  const int g = (id & 7) | (((id >> 3) & 1) << 3);  // (b,kvh) group 0..15
  const int b = g >> 2, kvh = g & 3;
  const int hi = (id >> 4) & 3;
  const int pr = (id >> 6) & 3;
  const int h = kvh * 4 + hi;

  const int t = threadIdx.x;
  const int l = t & 63, w = t >> 6;  // 8 waves
  const int lr = l & 15, lk = l >> 4;
  const int lr8 = lr & 7;

  __shared__ __bf16 Ks[2][64 * 128];
  __shared__ __bf16 Vs[2][128 * 64];
  __shared__ __bf16 Ps[8][16 * 64];

  const size_t rb = (size_t)b * 1024;
  const __bf16* Kg0 = qkv + rb * 3072 + 2048 + kvh * 128;
  const __bf16* Vtb = vt + (size_t)(b * 4 + kvh) * 128 * 1024;

  // staging address constants
  const int koff0 = t * 8;
  const int krow0 = koff0 >> 7;
  const int kcol0 = (koff0 & 127) ^ ((krow0 & 7) << 3);
  const int koff1 = 4096 + t * 8;
  const int krow1 = koff1 >> 7;
  const int kcol1 = (koff1 & 127) ^ ((krow1 & 7) << 3);
  const int voff0 = t * 8, voff1 = 4096 + t * 8;

#pragma unroll 1
  for (int pass = 0; pass < 2; ++pass) {
    const int qt = pass ? (7 - pr) : pr;
    const int q0 = qt << 7;

    // Q fragments -> registers; wave w owns q-rows q0+w*16..+15
    bf16x8 aq[4];
    {
      const __bf16* qrow = qkv + (rb + q0 + w * 16 + lr) * 3072 + h * 128 + lk * 8;
#pragma unroll
      for (int kk = 0; kk < 4; ++kk) aq[kk] = *(const bf16x8*)(qrow + kk * 32);
    }

    float m_i[4], l_i[4];
    f32x4 o[8] = {};
#pragma unroll
    for (int i = 0; i < 4; ++i) {
      m_i[i] = -1e30f;
      l_i[i] = 0.0f;
    }

    const int rowg0 = q0 + w * 16 + lk * 4;
    const int wmin = q0 + w * 16;
    const int wmax = wmin + 15;
    const int nt = 2 * qt + 2;

    // prologue: stage tile 0 into buf 0
    gload_lds16(Kg0 + (size_t)krow0 * 3072 + kcol0, &Ks[0][0] + koff0);
    gload_lds16(Kg0 + (size_t)krow1 * 3072 + kcol1, &Ks[0][0] + koff1);
    gload_lds16(Vtb + (size_t)(voff0 >> 6) * 1024 + (voff0 & 63), &Vs[0][0] + voff0);
    gload_lds16(Vtb + (size_t)(voff1 >> 6) * 1024 + (voff1 & 63), &Vs[0][0] + voff1);
    __syncthreads();  // drains vmcnt -> buf0 ready

    for (int tt = 0; tt < nt; ++tt) {
      const int kv0 = tt * 64;
      const int cur = tt & 1;
      // issue next tile's staging first (async; lands in other buffer)
      if (tt + 1 < nt) {
        const int nkv = kv0 + 64;
        const __bf16* Kg = Kg0 + (size_t)nkv * 3072;
        __bf16* kd = &Ks[cur ^ 1][0];
        __bf16* vd = &Vs[cur ^ 1][0];
        gload_lds16(Kg + (size_t)krow0 * 3072 + kcol0, kd + koff0);
        gload_lds16(Kg + (size_t)krow1 * 3072 + kcol1, kd + koff1);
        gload_lds16(Vtb + (size_t)(voff0 >> 6) * 1024 + nkv + (voff0 & 63), vd + voff0);
        gload_lds16(Vtb + (size_t)(voff1 >> 6) * 1024 + nkv + (voff1 & 63), vd + voff1);
      }

      if (kv0 <= wmax) {  // wave has unmasked work in this tile
        // S = Q K^T (log2-domain: q pre-scaled in normrope)
        f32x4 sacc[4] = {};
#pragma unroll
        for (int kk = 0; kk < 4; ++kk) {
#pragma unroll
          for (int n = 0; n < 4; ++n) {
            const bf16x8 bk = *(const bf16x8*)&Ks[cur][(n * 16 + lr) * 128 +
                                                      ((kk * 32 + lk * 8) ^ (lr8 << 3))];
            sacc[n] = MFMA16x16x32(aq[kk], bk, sacc[n]);
          }
        }

        // causal mask (diagonal tiles only) + online softmax (exp2)
        float pm[4];
#pragma unroll
        for (int i = 0; i < 4; ++i) pm[i] = -1e30f;
        if (kv0 + 63 > wmin) {
#pragma unroll
          for (int n = 0; n < 4; ++n) {
            const int colg = kv0 + n * 16 + lr;
#pragma unroll
            for (int i = 0; i < 4; ++i) {
              if (colg > rowg0 + i) sacc[n][i] = -1e30f;
              pm[i] = fmaxf(pm[i], sacc[n][i]);
            }
          }
        } else {
#pragma unroll
          for (int n = 0; n < 4; ++n)
#pragma unroll
            for (int i = 0; i < 4; ++i) pm[i] = fmaxf(pm[i], sacc[n][i]);
        }
#pragma unroll
        for (int i = 0; i < 4; ++i) {
          pm[i] = fmaxf(pm[i], __shfl_xor(pm[i], 1));
          pm[i] = fmaxf(pm[i], __shfl_xor(pm[i], 2));
          pm[i] = fmaxf(pm[i], __shfl_xor(pm[i], 4));
          pm[i] = fmaxf(pm[i], __shfl_xor(pm[i], 8));
        }
        float alpha[4], rs[4];
#pragma unroll
        for (int i = 0; i < 4; ++i) {
          const float mn = fmaxf(m_i[i], pm[i]);
          alpha[i] = EXP2(m_i[i] - mn);
          m_i[i] = mn;
          rs[i] = 0.0f;
        }
#pragma unroll
        for (int n = 0; n < 4; ++n) {
#pragma unroll
          for (int i = 0; i < 4; ++i) {
            const float p = EXP2(sacc[n][i] - m_i[i]);
            rs[i] += p;
            const int prow = lk * 4 + i;
            Ps[w][prow * 64 + ((n * 16 + lr) ^ ((prow & 7) << 3))] = (__bf16)p;
          }
        }
#pragma unroll
        for (int i = 0; i < 4; ++i) {
          rs[i] += __shfl_xor(rs[i], 1);
          rs[i] += __shfl_xor(rs[i], 2);
          rs[i] += __shfl_xor(rs[i], 4);
          rs[i] += __shfl_xor(rs[i], 8);
          l_i[i] = l_i[i] * alpha[i] + rs[i];
        }
#pragma unroll
        for (int f = 0; f < 8; ++f)
#pragma unroll
          for (int i = 0; i < 4; ++i) o[f][i] *= alpha[i];

        // O += P V
#pragma unroll
        for (int ks = 0; ks < 2; ++ks) {
          const bf16x8 pa =
              *(const bf16x8*)&Ps[w][lr * 64 + ((ks * 32 + lk * 8) ^ (lr8 << 3))];
#pragma unroll
          for (int f = 0; f < 8; ++f) {
            const bf16x8 vb = *(const bf16x8*)&Vs[cur][(f * 16 + lr) * 64 +
                                                       ((ks * 32 + lk * 8) ^ (lr8 << 3))];
            o[f] = MFMA16x16x32(pa, vb, o[f]);
          }
        }
      }

      __syncthreads();  // next tile staged (vmcnt drained) + all LDS reads done
    }

    // epilogue: normalize, v-projection correction, store bf16
#pragma unroll
    for (int i = 0; i < 4; ++i) {
      const int sg = rowg0 + i;
      const size_t mg = rb + sg;
      const __bf16* vp = qkv + mg * 3072 + 2560 + kvh * 128;
      const float invl = 1.0f / l_i[i];
      float vvv[8], yvv[8];
      float dyv = 0.0f, dvv = 0.0f;
#pragma unroll
      for (int f = 0; f < 8; ++f) {
        const float vf = (float)vp[f * 16 + lr];
        const float yf = o[f][i] * invl;
        vvv[f] = vf;
        yvv[f] = yf;
        dyv += yf * vf;
        dvv += vf * vf;
      }
#pragma unroll
      for (int off = 1; off < 16; off <<= 1) {
        dyv += __shfl_xor(dyv, off);
        dvv += __shfl_xor(dvv, off);
      }
      const float proj = dyv / fmaxf(dvv, 1e-6f);
      __bf16* yp = y + mg * 2048 + h * 128;
#pragma unroll
      for (int f = 0; f < 8; ++f) yp[f * 16 + lr] = (__bf16)(yvv[f] - proj * vvv[f]);
    }
  }
}

// ---------------------------------------------------------------------------
extern "C" void kernel_launch(void* const* d_in, const int* in_sizes, int n_in,
                              void* d_out, int out_size, void* d_ws, size_t ws_size,
                              hipStream_t stream) {
  const float* x = (const float*)d_in[0];
  const float* Wq = (const float*)d_in[2];
  const float* Wk = (const float*)d_in[3];
  const float* Wv = (const float*)d_in[4];
  const float* Wp = (const float*)d_in[5];
  float* out = (float*)d_out;

  __bf16* xb = (__bf16*)d_ws;                // 4096x2048
  __bf16* Wb = xb + (size_t)4096 * 2048;     // 3072x2048  [Wq;Wk;Wv]
  __bf16* Wpb = Wb + (size_t)3072 * 2048;    // 2048x2048
  __bf16* qkv = Wpb + (size_t)2048 * 2048;   // 4096x3072
  __bf16* yb = qkv + (size_t)4096 * 3072;    // 4096x2048
  __bf16* vt = xb;  // reuse xb region after qkv GEMM (4*4*128*1024 elems)

  cast_f2b<<<1024, 256, 0, stream>>>(x, xb, 4096 * 2048 / 4);
  cast3_f2b<<<768, 256, 0, stream>>>(Wq, Wk, Wv, Wb);
  cast_f2b<<<512, 256, 0, stream>>>(Wp, Wpb, 2048 * 2048 / 4);

  gemm256<256, __bf16><<<192, 512, 0, stream>>>(xb, Wb, qkv, 3072, 2048, 12);
  normrope<<<20480, 256, 0, stream>>>(qkv);
  vtrans<<<256, 256, 0, stream>>>(qkv, vt);
  attn_fwd<<<256, 512, 0, stream>>>(qkv, vt, yb);
  gemm256<128, float><<<256, 512, 0, stream>>>(yb, Wpb, out, 2048, 2048, 16);
}

// Round 10
// 182.505 us; speedup vs baseline: 1.2179x; 1.2179x over previous
//
#include <hip/hip_runtime.h>

// ---------------------------------------------------------------------------
// SelfAttention fused pipeline for MI355X (gfx950)
// B=4 S=1024 DIM=2048 H=16 KV=4 HD=128 ROPE_DIM=64
//
// Stages (all on `stream`), 5 launches:
//  1) prep: casts fp32->bf16 (x | Wq|Wk|Wv | Wproj) + rope cos/sin table
//  2) gemm_bt<FUSE>: qkv = xb @ Wcat^T (128^2, dbuf stage-early, swizzled LDS)
//     epilogue fuses RMSNorm + partial RoPE + q log2-prescale for q/k heads
//  3) vtrans: V -> Vt_global[b,kvh][d][kv] (pre-swizzled for LDS staging)
//  4) attn_fwd: causal flash attention + v-proj correction -> y bf16
//     (persistent-balanced 256 blocks, 18 kv-iters each, setprio on MFMA)
//  5) gemm_bt: out = y @ Wproj^T (fp32 out)
// ---------------------------------------------------------------------------

typedef __attribute__((ext_vector_type(8))) __bf16 bf16x8;
typedef __attribute__((ext_vector_type(4))) __bf16 bf16x4;
typedef __attribute__((ext_vector_type(4))) float f32x4;

static_assert(sizeof(__bf16) == 2, "bf16 size");

#define MFMA16x16x32(a, b, c) __builtin_amdgcn_mfma_f32_16x16x32_bf16((a), (b), (c), 0, 0, 0)

#if __has_builtin(__builtin_amdgcn_exp2f)
#define EXP2(x) __builtin_amdgcn_exp2f(x)
#else
#define EXP2(x) exp2f(x)
#endif

__device__ __forceinline__ void gload_lds16(const void* g, void* l) {
  __builtin_amdgcn_global_load_lds((const __attribute__((address_space(1))) void*)g,
                                   (__attribute__((address_space(3))) void*)l, 16, 0, 0);
}

// ---------------- 1) prep: all casts + rope table, one kernel ----------------
__global__ __launch_bounds__(256) void prep(const float* __restrict__ x,
                                            const float* __restrict__ wq,
                                            const float* __restrict__ wk,
                                            const float* __restrict__ wv,
                                            const float* __restrict__ wp,
                                            __bf16* __restrict__ xb,
                                            __bf16* __restrict__ wb,
                                            __bf16* __restrict__ wpb,
                                            float2* __restrict__ tab) {
  constexpr int NX = 2097152;   // 4096*2048/4
  constexpr int NW1 = 1048576;  // 2048*2048/4
  constexpr int NW2 = 262144;   // 512*2048/4
  constexpr int NP = 1048576;   // 2048*2048/4
  constexpr int NT = 32768;     // 1024*32 rope table entries
  constexpr int TOT = NX + NW1 + 2 * NW2 + NP + NT;
  auto cast4 = [](const float* s, __bf16* d, int i) {
    f32x4 v = ((const f32x4*)s)[i];
    bf16x4 o;
    o[0] = (__bf16)v[0];
    o[1] = (__bf16)v[1];
    o[2] = (__bf16)v[2];
    o[3] = (__bf16)v[3];
    ((bf16x4*)d)[i] = o;
  };
  int i = blockIdx.x * blockDim.x + threadIdx.x;
  const int stride = gridDim.x * blockDim.x;
  for (; i < TOT; i += stride) {
    int j = i;
    if (j < NX) {
      cast4(x, xb, j);
    } else if ((j -= NX) < NW1) {
      cast4(wq, wb, j);
    } else if ((j -= NW1) < NW2) {
      cast4(wk, wb + (size_t)NW1 * 4, j);
    } else if ((j -= NW2) < NW2) {
      cast4(wv, wb + (size_t)(NW1 + NW2) * 4, j);
    } else if ((j -= NW2) < NP) {
      cast4(wp, wpb, j);
    } else {
      j -= NP;  // rope table: entry (s, jj)
      const int s = j >> 5, jj = j & 31;
      const float inv = powf(10000.0f, -(float)jj * 0.03125f);
      const float ang = (float)s * inv;
      tab[j] = make_float2(cosf(ang), sinf(ang));
    }
  }
}

// ---------------- 2/5) B^T GEMM: 128^2 dbuf stage-early + swizzle ------------
// C[M,N] = A[M,K]*B[N,K]^T. 128x128 tile, BK=32, 4 waves (2x2) of 64x64.
// Double-buffered LDS, stage(kt+1) issued before compute(kt); LDS col-group
// swizzled by (row>>1)&3 (verified conflict-free, R8) via inverse-swizzled
// global source. 1-D grid, XCD-chunked (nwg%8==0), bm-major within chunk.
// FUSE epilogue (QKV only): each 128-col tile = one q/k head ->
// RMSNorm (shfl butterfly + 1KB LDS cross-wave) + partial RoPE (pairs
// (j,j+32) = acc[m][n] vs acc[m][n+2], same lane) + q log2-domain prescale.
template <typename CT, bool FUSE>
__global__ __launch_bounds__(256) void gemm_bt(const __bf16* __restrict__ A,
                                               const __bf16* __restrict__ B,
                                               CT* __restrict__ C, int N, int K, int nbn,
                                               const float2* __restrict__ tab) {
  __shared__ __bf16 As[2][128 * 32];
  __shared__ __bf16 Bs[2][128 * 32];
  const int nwg = gridDim.x;
  const int id = blockIdx.x;
  const int xid = (id & 7) * (nwg >> 3) + (id >> 3);
  const int bm = xid / nbn;
  const int bn = xid - bm * nbn;
  const int t = threadIdx.x;
  const int l = t & 63, w = t >> 6;
  const int wr = w >> 1, wc = w & 1;
  const int lr = l & 15, lk = l >> 4;
  const __bf16* Ab = A + (size_t)bm * 128 * K;
  const __bf16* Bb = B + (size_t)bn * 128 * K;
  const int srow = t >> 2;                              // 0..63 (also +64)
  const int scol = ((t & 3) ^ ((srow >> 1) & 3)) << 3;  // inverse swizzle on src
  f32x4 acc[4][4] = {};

  auto stage = [&](int k0, int buf) {
    gload_lds16(Ab + (size_t)srow * K + k0 + scol, &As[buf][t * 8]);
    gload_lds16(Ab + (size_t)(srow + 64) * K + k0 + scol, &As[buf][2048 + t * 8]);
    gload_lds16(Bb + (size_t)srow * K + k0 + scol, &Bs[buf][t * 8]);
    gload_lds16(Bb + (size_t)(srow + 64) * K + k0 + scol, &Bs[buf][2048 + t * 8]);
  };

  stage(0, 0);
  __syncthreads();  // buf0 ready (barrier drains vmcnt)

  const int NT = K >> 5;
  for (int kt = 0; kt < NT; ++kt) {
    const int cur = kt & 1;
    if (kt + 1 < NT) stage((kt + 1) << 5, cur ^ 1);  // issue next tile first

    bf16x8 af[4], bfr[4];
#pragma unroll
    for (int m = 0; m < 4; ++m) {
      const int row = wr * 64 + m * 16 + lr;
      af[m] = *(const bf16x8*)&As[cur][row * 32 + ((lk ^ ((row >> 1) & 3)) << 3)];
    }
#pragma unroll
    for (int n = 0; n < 4; ++n) {
      const int row = wc * 64 + n * 16 + lr;
      bfr[n] = *(const bf16x8*)&Bs[cur][row * 32 + ((lk ^ ((row >> 1) & 3)) << 3)];
    }
#pragma unroll
    for (int m = 0; m < 4; ++m)
#pragma unroll
      for (int n = 0; n < 4; ++n) acc[m][n] = MFMA16x16x32(af[m], bfr[n], acc[m][n]);

    __syncthreads();  // next tile staged (vmcnt drained) + all LDS reads done
  }

  if constexpr (FUSE) {
    // bn 0..15 = q heads, 16..19 = k heads, 20..23 = v (plain store)
    if (bn < 20) {
      __shared__ float Ls[2][128];
      // per-row sum of squares: butterfly over the 16 lr-lanes (= 16 cols)
      float ssp[4][4];
#pragma unroll
      for (int m = 0; m < 4; ++m)
#pragma unroll
        for (int i = 0; i < 4; ++i) {
          float s = 0.0f;
#pragma unroll
          for (int n = 0; n < 4; ++n) s += acc[m][n][i] * acc[m][n][i];
#pragma unroll
          for (int off = 1; off < 16; off <<= 1) s += __shfl_xor(s, off);
          ssp[m][i] = s;
        }
      if (lr == 0) {
#pragma unroll
        for (int m = 0; m < 4; ++m)
#pragma unroll
          for (int i = 0; i < 4; ++i)
            Ls[wc][wr * 64 + m * 16 + lk * 4 + i] = ssp[m][i];
      }
      __syncthreads();
      const bool isq = (bn < 16);
      const float qs = isq ? 0.1275174457f : 1.0f;  // (1/sqrt(128))*log2(e)
#pragma unroll
      for (int m = 0; m < 4; ++m) {
#pragma unroll
        for (int i = 0; i < 4; ++i) {
          const int rl = wr * 64 + m * 16 + lk * 4 + i;
          const int rg = bm * 128 + rl;
          const float sc =
              rsqrtf((Ls[0][rl] + Ls[1][rl]) * (1.0f / 128.0f) +
                     1.1920928955078125e-07f) *
              qs;
          CT* Cr = C + (size_t)rg * N + bn * 128;
          if (wc == 0) {
            const int s = rg & 1023;
#pragma unroll
            for (int n = 0; n < 2; ++n) {
              const int j = n * 16 + lr;
              const float2 cs = tab[s * 32 + j];
              const float x1 = acc[m][n][i], x2 = acc[m][n + 2][i];
              Cr[j] = (CT)((x1 * cs.x + x2 * cs.y) * sc);
              Cr[j + 32] = (CT)((-x1 * cs.y + x2 * cs.x) * sc);
            }
          } else {
#pragma unroll
            for (int n = 0; n < 4; ++n)
              Cr[64 + n * 16 + lr] = (CT)(acc[m][n][i] * sc);
          }
        }
      }
      return;
    }
  }

#pragma unroll
  for (int m = 0; m < 4; ++m) {
    const int row0 = bm * 128 + wr * 64 + m * 16 + lk * 4;
#pragma unroll
    for (int n = 0; n < 4; ++n) {
      const int col = bn * 128 + wc * 64 + n * 16 + lr;
#pragma unroll
      for (int i = 0; i < 4; ++i) C[(size_t)(row0 + i) * N + col] = (CT)acc[m][n][i];
    }
  }
}

// ---------------- 3) V transpose: Vt[b,kvh][d][kv ^ ((d&7)<<3)] -------------
__global__ __launch_bounds__(256) void vtrans(const __bf16* __restrict__ qkv,
                                              __bf16* __restrict__ vt) {
  __shared__ __bf16 L[64 * 128];
  const int tile = blockIdx.x;  // (b*4+kvh)*16 + st
  const int st = tile & 15, bk = tile >> 4;
  const int b = bk >> 2, kvh = bk & 3;
  const int t = threadIdx.x;
  const int s0 = st * 64;
  const __bf16* src = qkv + ((size_t)(b * 1024 + s0)) * 3072 + 2560 + kvh * 128;
#pragma unroll
  for (int r = 0; r < 4; ++r) {
    const int off = r * 2048 + t * 8;
    const int s = off >> 7, d = off & 127;
    bf16x8 v = *(const bf16x8*)(src + (size_t)s * 3072 + d);
    *(bf16x8*)&L[s * 128 + (d ^ ((s & 7) << 3) ^ (((s >> 3) & 7) << 3))] = v;
  }
  __syncthreads();
  __bf16* dst = vt + (size_t)bk * 128 * 1024;
#pragma unroll
  for (int r = 0; r < 4; ++r) {
    const int off = r * 2048 + t * 8;
    const int d = off >> 6, sc = off & 63;
    bf16x8 v;
#pragma unroll
    for (int j = 0; j < 8; ++j) {
      const int s = sc + j;
      v[j] = L[s * 128 + (d ^ ((s & 7) << 3) ^ (((s >> 3) & 7) << 3))];
    }
    *(bf16x8*)&dst[(size_t)d * 1024 + ((s0 + sc) ^ ((d & 7) << 3))] = v;
  }
}

// ---------------- 4) causal flash attention + v-projection correction ------
// 256 blocks (=1/CU), each handles ONE (b,h) and TWO q-tiles (pr, 7-pr)
// sequentially -> exactly 18 kv-iterations/block. XCD grouping: blocks of one
// (b,kvh) group share an XCD (id&7) so K/V stays L2-resident.
__global__ __launch_bounds__(512) void attn_fwd(const __bf16* __restrict__ qkv,
                                                const __bf16* __restrict__ vt,
                                                __bf16* __restrict__ y) {
  const int id = blockIdx.x;
  const int g = (id & 7) | (((id >> 3) & 1) << 3);  // (b,kvh) group 0..15
  const int b = g >> 2, kvh = g & 3;
  const int hi = (id >> 4) & 3;
  const int pr = (id >> 6) & 3;
  const int h = kvh * 4 + hi;

  const int t = threadIdx.x;
  const int l = t & 63, w = t >> 6;  // 8 waves
  const int lr = l & 15, lk = l >> 4;
  const int lr8 = lr & 7;

  __shared__ __bf16 Ks[2][64 * 128];
  __shared__ __bf16 Vs[2][128 * 64];
  __shared__ __bf16 Ps[8][16 * 64];

  const size_t rb = (size_t)b * 1024;
  const __bf16* Kg0 = qkv + rb * 3072 + 2048 + kvh * 128;
  const __bf16* Vtb = vt + (size_t)(b * 4 + kvh) * 128 * 1024;

  // staging address constants
  const int koff0 = t * 8;
  const int krow0 = koff0 >> 7;
  const int kcol0 = (koff0 & 127) ^ ((krow0 & 7) << 3);
  const int koff1 = 4096 + t * 8;
  const int krow1 = koff1 >> 7;
  const int kcol1 = (koff1 & 127) ^ ((krow1 & 7) << 3);
  const int voff0 = t * 8, voff1 = 4096 + t * 8;

#pragma unroll 1
  for (int pass = 0; pass < 2; ++pass) {
    const int qt = pass ? (7 - pr) : pr;
    const int q0 = qt << 7;

    // Q fragments -> registers; wave w owns q-rows q0+w*16..+15
    bf16x8 aq[4];
    {
      const __bf16* qrow = qkv + (rb + q0 + w * 16 + lr) * 3072 + h * 128 + lk * 8;
#pragma unroll
      for (int kk = 0; kk < 4; ++kk) aq[kk] = *(const bf16x8*)(qrow + kk * 32);
    }

    float m_i[4], l_i[4];
    f32x4 o[8] = {};
#pragma unroll
    for (int i = 0; i < 4; ++i) {
      m_i[i] = -1e30f;
      l_i[i] = 0.0f;
    }

    const int rowg0 = q0 + w * 16 + lk * 4;
    const int wmin = q0 + w * 16;
    const int wmax = wmin + 15;
    const int nt = 2 * qt + 2;

    // prologue: stage tile 0 into buf 0
    gload_lds16(Kg0 + (size_t)krow0 * 3072 + kcol0, &Ks[0][0] + koff0);
    gload_lds16(Kg0 + (size_t)krow1 * 3072 + kcol1, &Ks[0][0] + koff1);
    gload_lds16(Vtb + (size_t)(voff0 >> 6) * 1024 + (voff0 & 63), &Vs[0][0] + voff0);
    gload_lds16(Vtb + (size_t)(voff1 >> 6) * 1024 + (voff1 & 63), &Vs[0][0] + voff1);
    __syncthreads();  // drains vmcnt -> buf0 ready

    for (int tt = 0; tt < nt; ++tt) {
      const int kv0 = tt * 64;
      const int cur = tt & 1;
      // issue next tile's staging first (async; lands in other buffer)
      if (tt + 1 < nt) {
        const int nkv = kv0 + 64;
        const __bf16* Kg = Kg0 + (size_t)nkv * 3072;
        __bf16* kd = &Ks[cur ^ 1][0];
        __bf16* vd = &Vs[cur ^ 1][0];
        gload_lds16(Kg + (size_t)krow0 * 3072 + kcol0, kd + koff0);
        gload_lds16(Kg + (size_t)krow1 * 3072 + kcol1, kd + koff1);
        gload_lds16(Vtb + (size_t)(voff0 >> 6) * 1024 + nkv + (voff0 & 63), vd + voff0);
        gload_lds16(Vtb + (size_t)(voff1 >> 6) * 1024 + nkv + (voff1 & 63), vd + voff1);
      }

      if (kv0 <= wmax) {  // wave has unmasked work in this tile
        // S = Q K^T (log2-domain: q pre-scaled in gemm epilogue)
        f32x4 sacc[4] = {};
        __builtin_amdgcn_s_setprio(1);
#pragma unroll
        for (int kk = 0; kk < 4; ++kk) {
#pragma unroll
          for (int n = 0; n < 4; ++n) {
            const bf16x8 bk = *(const bf16x8*)&Ks[cur][(n * 16 + lr) * 128 +
                                                      ((kk * 32 + lk * 8) ^ (lr8 << 3))];
            sacc[n] = MFMA16x16x32(aq[kk], bk, sacc[n]);
          }
        }
        __builtin_amdgcn_s_setprio(0);

        // causal mask (diagonal tiles only) + online softmax (exp2)
        float pm[4];
#pragma unroll
        for (int i = 0; i < 4; ++i) pm[i] = -1e30f;
        if (kv0 + 63 > wmin) {
#pragma unroll
          for (int n = 0; n < 4; ++n) {
            const int colg = kv0 + n * 16 + lr;
#pragma unroll
            for (int i = 0; i < 4; ++i) {
              if (colg > rowg0 + i) sacc[n][i] = -1e30f;
              pm[i] = fmaxf(pm[i], sacc[n][i]);
            }
          }
        } else {
#pragma unroll
          for (int n = 0; n < 4; ++n)
#pragma unroll
            for (int i = 0; i < 4; ++i) pm[i] = fmaxf(pm[i], sacc[n][i]);
        }
#pragma unroll
        for (int i = 0; i < 4; ++i) {
          pm[i] = fmaxf(pm[i], __shfl_xor(pm[i], 1));
          pm[i] = fmaxf(pm[i], __shfl_xor(pm[i], 2));
          pm[i] = fmaxf(pm[i], __shfl_xor(pm[i], 4));
          pm[i] = fmaxf(pm[i], __shfl_xor(pm[i], 8));
        }
        float alpha[4], rs[4];
#pragma unroll
        for (int i = 0; i < 4; ++i) {
          const float mn = fmaxf(m_i[i], pm[i]);
          alpha[i] = EXP2(m_i[i] - mn);
          m_i[i] = mn;
          rs[i] = 0.0f;
        }
#pragma unroll
        for (int n = 0; n < 4; ++n) {
#pragma unroll
          for (int i = 0; i < 4; ++i) {
            const float p = EXP2(sacc[n][i] - m_i[i]);
            rs[i] += p;
            const int prow = lk * 4 + i;
            Ps[w][prow * 64 + ((n * 16 + lr) ^ ((prow & 7) << 3))] = (__bf16)p;
          }
        }
#pragma unroll
        for (int i = 0; i < 4; ++i) {
          rs[i] += __shfl_xor(rs[i], 1);
          rs[i] += __shfl_xor(rs[i], 2);
          rs[i] += __shfl_xor(rs[i], 4);
          rs[i] += __shfl_xor(rs[i], 8);
          l_i[i] = l_i[i] * alpha[i] + rs[i];
        }
#pragma unroll
        for (int f = 0; f < 8; ++f)
#pragma unroll
          for (int i = 0; i < 4; ++i) o[f][i] *= alpha[i];

        // O += P V
        __builtin_amdgcn_s_setprio(1);
#pragma unroll
        for (int ks = 0; ks < 2; ++ks) {
          const bf16x8 pa =
              *(const bf16x8*)&Ps[w][lr * 64 + ((ks * 32 + lk * 8) ^ (lr8 << 3))];
#pragma unroll
          for (int f = 0; f < 8; ++f) {
            const bf16x8 vb = *(const bf16x8*)&Vs[cur][(f * 16 + lr) * 64 +
                                                       ((ks * 32 + lk * 8) ^ (lr8 << 3))];
            o[f] = MFMA16x16x32(pa, vb, o[f]);
          }
        }
        __builtin_amdgcn_s_setprio(0);
      }

      __syncthreads();  // next tile staged (vmcnt drained) + all LDS reads done
    }

    // epilogue: normalize, v-projection correction, store bf16
#pragma unroll
    for (int i = 0; i < 4; ++i) {
      const int sg = rowg0 + i;
      const size_t mg = rb + sg;
      const __bf16* vp = qkv + mg * 3072 + 2560 + kvh * 128;
      const float invl = 1.0f / l_i[i];
      float vvv[8], yvv[8];
      float dyv = 0.0f, dvv = 0.0f;
#pragma unroll
      for (int f = 0; f < 8; ++f) {
        const float vf = (float)vp[f * 16 + lr];
        const float yf = o[f][i] * invl;
        vvv[f] = vf;
        yvv[f] = yf;
        dyv += yf * vf;
        dvv += vf * vf;
      }
#pragma unroll
      for (int off = 1; off < 16; off <<= 1) {
        dyv += __shfl_xor(dyv, off);
        dvv += __shfl_xor(dvv, off);
      }
      const float proj = dyv / fmaxf(dvv, 1e-6f);
      __bf16* yp = y + mg * 2048 + h * 128;
#pragma unroll
      for (int f = 0; f < 8; ++f) yp[f * 16 + lr] = (__bf16)(yvv[f] - proj * vvv[f]);
    }
  }
}

// ---------------------------------------------------------------------------
extern "C" void kernel_launch(void* const* d_in, const int* in_sizes, int n_in,
                              void* d_out, int out_size, void* d_ws, size_t ws_size,
                              hipStream_t stream) {
  const float* x = (const float*)d_in[0];
  const float* Wq = (const float*)d_in[2];
  const float* Wk = (const float*)d_in[3];
  const float* Wv = (const float*)d_in[4];
  const float* Wp = (const float*)d_in[5];
  float* out = (float*)d_out;

  __bf16* xb = (__bf16*)d_ws;                // 4096x2048
  __bf16* Wb = xb + (size_t)4096 * 2048;     // 3072x2048  [Wq;Wk;Wv]
  __bf16* Wpb = Wb + (size_t)3072 * 2048;    // 2048x2048
  __bf16* qkv = Wpb + (size_t)2048 * 2048;   // 4096x3072
  __bf16* yb = qkv + (size_t)4096 * 3072;    // 4096x2048
  float2* tab = (float2*)(yb + (size_t)4096 * 2048);  // 1024x32 cos/sin
  __bf16* vt = xb;  // reuse xb region after qkv GEMM (4*4*128*1024 elems)

  prep<<<2048, 256, 0, stream>>>(x, Wq, Wk, Wv, Wp, xb, Wb, Wpb, tab);

  gemm_bt<__bf16, true><<<768, 256, 0, stream>>>(xb, Wb, qkv, 3072, 2048, 24, tab);
  vtrans<<<256, 256, 0, stream>>>(qkv, vt);
  attn_fwd<<<256, 512, 0, stream>>>(qkv, vt, yb);
  gemm_bt<float, false><<<512, 256, 0, stream>>>(yb, Wpb, out, 2048, 2048, 16, nullptr);
}